// Round 12
// baseline (65.904 us; speedup 1.0000x reference)
//
#include <hip/hip_runtime.h>
#include <hip/hip_bf16.h>

#define B_ 4
#define Q_ 256
#define K_ 1024
#define D_ 256
#define NVPAD 640
#define SCPAD 640
#define LOG2E 1.44269504f

__device__ __forceinline__ float fexp2(float x) {
    float r; asm("v_exp_f32 %0, %1" : "=v"(r) : "v"(x)); return r;
}
__device__ __forceinline__ float frcp(float x) {
    float r; asm("v_rcp_f32 %0, %1" : "=v"(r) : "v"(x)); return r;
}

// Grid = B, 64 threads. kidx[slot]=k, slot_of[k]=slot or -1, nvalid.
__global__ void compact_kernel(const int* __restrict__ mask,
                               ushort* __restrict__ kidx,
                               short* __restrict__ slot_of,
                               int* __restrict__ nvalid) {
    const int b = blockIdx.x, lane = threadIdx.x;
    const int* m = mask + b * K_;
    const int base = lane * 16;
    int cnt = 0;
#pragma unroll
    for (int i = 0; i < 16; ++i) cnt += (m[base + i] != 0);
    int inc = cnt;
#pragma unroll
    for (int d = 1; d < 64; d <<= 1) {
        int tt = __shfl_up(inc, d);
        if (lane >= d) inc += tt;
    }
    const int total = __shfl(inc, 63);
    int pos = inc - cnt;
    ushort* kb = kidx + b * K_;
    short* so  = slot_of + b * K_;
    for (int i = 0; i < 16; ++i) {
        int kk = base + i;
        if (m[kk] != 0) { kb[pos] = (ushort)kk; so[kk] = (short)pos; ++pos; }
        else so[kk] = -1;
    }
    for (int j = total + lane; j < K_; j += 64) kb[j] = 0;
    if (lane == 0) nvalid[b] = total;
}

// Grid (80,4), 256 thr. x<16: qpE[row][e] = exp2(c*q@Wq) row-major.
// x>=16: kpC[b][e4][slot]{4e} = exp2(c*k@Wk)  (tiled-transposed compacted).
__global__ __launch_bounds__(256) void proj_kernel(const float* __restrict__ q,
                                                   const float* __restrict__ k,
                                                   const float* __restrict__ Wq,
                                                   const float* __restrict__ Wk,
                                                   const short* __restrict__ slot_of,
                                                   float* __restrict__ qpE,
                                                   float* __restrict__ kpC,
                                                   float scale) {
    const int t = threadIdx.x;
    const bool isQ = blockIdx.x < 16;
    const float* A; const float* W; int m0;
    if (isQ) { A = q; W = Wq; m0 = blockIdx.x * 64; }
    else     { A = k; W = Wk; m0 = (blockIdx.x - 16) * 64; }

    __shared__ float As[16][65];
    __shared__ float Ws[16][64];
    __shared__ short s_slot[64];
    if (!isQ && t < 64) s_slot[t] = slot_of[m0 + t];

    const int tx = t & 15, ty = t >> 4;
    const int n0 = blockIdx.y * 64;
    const int ar = t >> 2, ac = (t & 3) * 4;
    const int wr = t >> 4, wc = (t & 15) * 4;
    float c[4][4] = {};
    for (int kb = 0; kb < 256; kb += 16) {
        __syncthreads();
        float4 av = *(const float4*)(A + (size_t)(m0 + ar) * 256 + kb + ac);
        As[ac + 0][ar] = av.x; As[ac + 1][ar] = av.y;
        As[ac + 2][ar] = av.z; As[ac + 3][ar] = av.w;
        float4 wvv = *(const float4*)(W + (size_t)(kb + wr) * 256 + n0 + wc);
        wvv.x *= scale; wvv.y *= scale; wvv.z *= scale; wvv.w *= scale;
        *(float4*)(&Ws[wr][wc]) = wvv;
        __syncthreads();
#pragma unroll
        for (int kk = 0; kk < 16; ++kk) {
            float4 bv = *(const float4*)(&Ws[kk][tx * 4]);
#pragma unroll
            for (int i = 0; i < 4; ++i) {
                float a = As[kk][ty * 4 + i];
                c[i][0] = fmaf(a, bv.x, c[i][0]);
                c[i][1] = fmaf(a, bv.y, c[i][1]);
                c[i][2] = fmaf(a, bv.z, c[i][2]);
                c[i][3] = fmaf(a, bv.w, c[i][3]);
            }
        }
    }
    if (isQ) {
#pragma unroll
        for (int i = 0; i < 4; ++i) {
            float4 o = make_float4(fexp2(c[i][0]), fexp2(c[i][1]),
                                   fexp2(c[i][2]), fexp2(c[i][3]));
            *(float4*)(qpE + (size_t)(m0 + ty * 4 + i) * 256 + n0 + tx * 4) = o;
        }
    } else {
        const int b = m0 >> 10;
        float* kpCb = kpC + (size_t)b * 64 * NVPAD * 4;
        const int e4 = (n0 + tx * 4) >> 2;
#pragma unroll
        for (int i = 0; i < 4; ++i) {
            const int sl = s_slot[ty * 4 + i];
            if (sl >= 0) {
                float4 o = make_float4(fexp2(c[i][0]), fexp2(c[i][1]),
                                       fexp2(c[i][2]), fexp2(c[i][3]));
                *(float4*)(kpCb + ((size_t)e4 * NVPAD + sl) * 4) = o;
            }
        }
    }
}

// Grid = 512 = B * 128 qpairs, 512 threads. Thread owns slot; per eg:
// 1 coalesced f4 kpC load + 3 LDS b128 broadcasts + 8x{fma,rcp,fma}x2q.
// Writes raw scores to scW. No reductions, 1 barrier.
__global__ __launch_bounds__(512, 2) void scores_kernel(const float* __restrict__ qpE,
                                                        const float* __restrict__ kpC,
                                                        const int* __restrict__ nvalid_g,
                                                        const float* __restrict__ wv,
                                                        float* __restrict__ scW) {
    __shared__ float4 sA0[64], sA1[64], sW[64];   // 3 KB

    const int tid = threadIdx.x;
    int bid = blockIdx.x;
    bid = (bid & 7) * 64 + (bid >> 3);            // bijective XCD swizzle
    const int b  = bid >> 7;
    const int qi = bid & 127;
    const int q0 = qi * 2;
    const int nv = nvalid_g[b];

    if (tid < 64)        sA0[tid]       = ((const float4*)(qpE + ((size_t)(b * Q_ + q0)     << 8)))[tid];
    else if (tid < 128)  sA1[tid - 64]  = ((const float4*)(qpE + ((size_t)(b * Q_ + q0 + 1) << 8)))[tid - 64];
    else if (tid < 192)  sW[tid - 128]  = ((const float4*)wv)[tid - 128];
    __syncthreads();

    const float4* Bp = (const float4*)kpC + (size_t)b * 64 * NVPAD;
    float* sc0 = scW + (size_t)(b * Q_ + q0) * SCPAD;
    float* sc1 = sc0 + SCPAD;

    for (int s = tid; s < nv; s += 512) {
        float a0 = 0.f, a1 = 0.f;
#pragma unroll 8
        for (int eg = 0; eg < 64; ++eg) {
            float4 Bv = Bp[(size_t)eg * NVPAD + s];   // per-lane f4, wave-coalesced
            float4 A0 = sA0[eg], A1 = sA1[eg], W4 = sW[eg];   // LDS broadcast
            a0 = fmaf(W4.x, frcp(fmaf(A0.x, Bv.x, 1.f)), a0);
            a1 = fmaf(W4.x, frcp(fmaf(A1.x, Bv.x, 1.f)), a1);
            a0 = fmaf(W4.y, frcp(fmaf(A0.y, Bv.y, 1.f)), a0);
            a1 = fmaf(W4.y, frcp(fmaf(A1.y, Bv.y, 1.f)), a1);
            a0 = fmaf(W4.z, frcp(fmaf(A0.z, Bv.z, 1.f)), a0);
            a1 = fmaf(W4.z, frcp(fmaf(A1.z, Bv.z, 1.f)), a1);
            a0 = fmaf(W4.w, frcp(fmaf(A0.w, Bv.w, 1.f)), a0);
            a1 = fmaf(W4.w, frcp(fmaf(A1.w, Bv.w, 1.f)), a1);
        }
        sc0[s] = -2.f * a0;
        sc1[s] = -2.f * a1;
    }
}

// Grid = 512 = B * 64 qquads * 2 d-halves, 512 threads.
// Softmax (4 waves own 4 q rows) then PV on a 128-float d-slice of v.
__global__ __launch_bounds__(512, 2) void smpv_kernel(const float* __restrict__ scW,
                                                      const float* __restrict__ v,
                                                      const ushort* __restrict__ kidx_g,
                                                      const int* __restrict__ nvalid_g,
                                                      float* __restrict__ out) {
    __shared__ float  s_p[4][SCPAD];      // 10 KB : unnormalized probs
    __shared__ ushort s_kidx[NVPAD];      //  1.3 KB
    __shared__ float4 s_pv[16][4][32];    // 32 KB : PV partials
    __shared__ float  s_inv[4];

    const int tid = threadIdx.x;
    int bid = blockIdx.x;
    bid = (bid & 7) * 64 + (bid >> 3);    // bijective XCD swizzle
    const int b  = bid >> 7;
    const int r  = bid & 127;
    const int qg = r >> 1;                // 64 q-quads
    const int dh = r & 1;                 // d-half
    const int q0 = qg * 4;
    const int nv = nvalid_g[b];

    for (int j = tid; j < nv; j += 512) s_kidx[j] = kidx_g[b * K_ + j];

    const int lane = tid & 63;
    const int wave = tid >> 6;
    if (wave < 4) {
        const int qq = wave;
        const float* sc = scW + (size_t)(b * Q_ + q0 + qq) * SCPAD;
        float mx = -3.0e38f;
        for (int j = lane; j < nv; j += 64) mx = fmaxf(mx, sc[j]);
#pragma unroll
        for (int off = 32; off > 0; off >>= 1) mx = fmaxf(mx, __shfl_xor(mx, off));
        float sum = 0.f;
        for (int j = lane; j < nv; j += 64) {
            float e = fexp2((sc[j] - mx) * LOG2E);
            s_p[qq][j] = e;
            sum += e;
        }
#pragma unroll
        for (int off = 32; off > 0; off >>= 1) sum += __shfl_xor(sum, off);
        if (lane == 0) s_inv[qq] = frcp(sum);
    }
    __syncthreads();

    // ---- PV on d-slice: thread -> (dl = tid&31 of 32 f4, kq = tid>>5 of 16) ----
    {
        const int dl = tid & 31;
        const int kq = tid >> 5;
        float4 o0 = {0,0,0,0}, o1 = {0,0,0,0}, o2 = {0,0,0,0}, o3 = {0,0,0,0};
        const float4* v4 = (const float4*)(v + ((size_t)b * K_ << 8)) + dh * 32;
        for (int k = kq; k < nv; k += 16) {
            int vr = s_kidx[k];
            float4 vv = v4[((size_t)vr << 6) + dl];
            float p0 = s_p[0][k], p1 = s_p[1][k], p2 = s_p[2][k], p3 = s_p[3][k];
            o0.x = fmaf(p0, vv.x, o0.x); o0.y = fmaf(p0, vv.y, o0.y);
            o0.z = fmaf(p0, vv.z, o0.z); o0.w = fmaf(p0, vv.w, o0.w);
            o1.x = fmaf(p1, vv.x, o1.x); o1.y = fmaf(p1, vv.y, o1.y);
            o1.z = fmaf(p1, vv.z, o1.z); o1.w = fmaf(p1, vv.w, o1.w);
            o2.x = fmaf(p2, vv.x, o2.x); o2.y = fmaf(p2, vv.y, o2.y);
            o2.z = fmaf(p2, vv.z, o2.z); o2.w = fmaf(p2, vv.w, o2.w);
            o3.x = fmaf(p3, vv.x, o3.x); o3.y = fmaf(p3, vv.y, o3.y);
            o3.z = fmaf(p3, vv.z, o3.z); o3.w = fmaf(p3, vv.w, o3.w);
        }
        s_pv[kq][0][dl] = o0;
        s_pv[kq][1][dl] = o1;
        s_pv[kq][2][dl] = o2;
        s_pv[kq][3][dl] = o3;
        __syncthreads();
        if (tid < 128) {
            const int qq = tid >> 5, c = tid & 31;
            float4 s = {0, 0, 0, 0};
#pragma unroll
            for (int g = 0; g < 16; ++g) {
                float4 x = s_pv[g][qq][c];
                s.x += x.x; s.y += x.y; s.z += x.z; s.w += x.w;
            }
            const float inv = s_inv[qq];
            s.x *= inv; s.y *= inv; s.z *= inv; s.w *= inv;
            ((float4*)out)[((size_t)(b * Q_ + q0 + qq) << 6) + dh * 32 + c] = s;
        }
    }
}

extern "C" void kernel_launch(void* const* d_in, const int* in_sizes, int n_in,
                              void* d_out, int out_size, void* d_ws, size_t ws_size,
                              hipStream_t stream) {
    const float* q    = (const float*)d_in[0];
    const float* k    = (const float*)d_in[1];
    const float* v    = (const float*)d_in[2];
    const int*   mask = (const int*)d_in[3];
    const float* Wq   = (const float*)d_in[4];
    const float* Wk   = (const float*)d_in[5];
    const float* wv   = (const float*)d_in[6];
    float* out = (float*)d_out;

    float* qpE    = (float*)d_ws;                            // 1 MB
    float* kpC    = qpE + (size_t)B_ * Q_ * D_;              // 4*64*640*4 f32 = 2.5 MB
    float* scW    = kpC + (size_t)B_ * 64 * NVPAD * 4;       // 4*256*640 f32 = 2.5 MB
    ushort* kidx  = (ushort*)(scW + (size_t)B_ * Q_ * SCPAD);// 8 KB
    short* slot_of = (short*)(kidx + (size_t)B_ * K_);       // 8 KB
    int* nvalid   = (int*)(slot_of + (size_t)B_ * K_);       // 16 B

    const float c2 = 2.885390082f;  // 2*log2(e)

    compact_kernel<<<dim3(B_), 64, 0, stream>>>(mask, kidx, slot_of, nvalid);
    proj_kernel<<<dim3(80, 4), 256, 0, stream>>>(q, k, Wq, Wk, slot_of, qpE, kpC, c2);
    scores_kernel<<<dim3(512), 512, 0, stream>>>(qpE, kpC, nvalid, wv, scW);
    smpv_kernel<<<dim3(512), 512, 0, stream>>>(scW, v, kidx, nvalid, out);
}